// Round 4
// baseline (197.777 us; speedup 1.0000x reference)
//
#include <hip/hip_runtime.h>
#include <hip/hip_fp16.h>

// EdgeMLP: out[e] = sigmoid( 0.5*dot(relu(af)+relu(ar), W2[:,1]-W2[:,0]) + (b2[1]-b2[0]) )
// Sym/antisym decomposition shares layer-1 work between fwd and rev MLPs:
//   P = 0.5*(W1[0:6]+W1[6:12]), M = 0.5*(W1[0:6]-W1[6:12])
//   cacc = b1 + P^T(xs+xt); macc = M^T(xs-xt)
//   af = cacc+macc+ea*w12, ar = cacc-macc+eaT*w12
//
// R3 post-mortem: VALU-issue bound (~250 VALU/edge ~= 81us model vs 78 measured).
// This round: packed fp16 + v_dot2_f32_f16 (fp32 accumulate) to halve the
// instruction count; 2 edges/thread to amortize addressing.
//
// d_ws layout:
//   float [0,10)  b1 (cacc init)     float [10] b2d
//   uint  [16,46)  P2[k][j]  (half2 of P[2k][j],P[2k+1][j]),  k<3, j<10
//   uint  [48,78)  M2[k][j]
//   uint  [80,85)  w12_2[jp] (half2 of W1[12][2jp],W1[12][2jp+1])
//   uint  [88,93)  w2d_2[jp] (half2 of 0.5*(W2[j][1]-W2[j][0]) pairs)
//   byte 4096+:    packed x, 16B/node = 6 fp16 + 2 pad

typedef _Float16 half2_t __attribute__((ext_vector_type(2)));
typedef _Float16 half8_t __attribute__((ext_vector_type(8)));
typedef float    float2_v __attribute__((ext_vector_type(2)));
typedef int      int2_v   __attribute__((ext_vector_type(2)));

union h2u { __half2 h; unsigned u; half2_t v; };

__global__ void prep(const float* __restrict__ W1, const float* __restrict__ b1,
                     const float* __restrict__ W2, const float* __restrict__ b2,
                     const float* __restrict__ x, float* __restrict__ wsf, int N) {
    int t = blockIdx.x * 256 + threadIdx.x;
    if (t < N) {   // pack x row t -> 6 fp16 + 2 pad (16B, aligned)
        const float2* xr = (const float2*)x;
        float2 a0 = xr[3 * t], a1 = xr[3 * t + 1], a2 = xr[3 * t + 2];
        union { __half2 h[4]; float4 f; } pk;
        pk.h[0] = __floats2half2_rn(a0.x, a0.y);
        pk.h[1] = __floats2half2_rn(a1.x, a1.y);
        pk.h[2] = __floats2half2_rn(a2.x, a2.y);
        pk.h[3] = __floats2half2_rn(0.0f, 0.0f);
        ((float4*)((char*)wsf + 4096))[t] = pk.f;
    }
    if (blockIdx.x == 0) {
        unsigned* wsu = (unsigned*)wsf;
        int u = threadIdx.x;
        if (u < 10) wsf[u] = b1[u];
        if (u == 0) wsf[10] = b2[1] - b2[0];
        if (u < 30) {                       // P2 / M2: i-pairs (2k, 2k+1)
            int k = u / 10, j = u % 10;
            float a0 = W1[(2 * k) * 10 + j],     c0 = W1[(2 * k + 6) * 10 + j];
            float a1 = W1[(2 * k + 1) * 10 + j], c1 = W1[(2 * k + 7) * 10 + j];
            h2u p, m;
            p.h = __floats2half2_rn(0.5f * (a0 + c0), 0.5f * (a1 + c1));
            m.h = __floats2half2_rn(0.5f * (a0 - c0), 0.5f * (a1 - c1));
            wsu[16 + u] = p.u;
            wsu[48 + u] = m.u;
        }
        if (u < 5) {                        // j-pairs (2u, 2u+1)
            h2u a, b;
            a.h = __floats2half2_rn(W1[120 + 2 * u], W1[120 + 2 * u + 1]);
            b.h = __floats2half2_rn(0.5f * (W2[(2 * u) * 2 + 1] - W2[(2 * u) * 2]),
                                    0.5f * (W2[(2 * u + 1) * 2 + 1] - W2[(2 * u + 1) * 2]));
            wsu[80 + u] = a.u;
            wsu[88 + u] = b.u;
        }
    }
}

static __device__ __forceinline__ float fdot2(half2_t a, half2_t b, float c) {
#if __has_builtin(__builtin_amdgcn_fdot2)
    return __builtin_amdgcn_fdot2(a, b, c, false);
#else
    return fmaf((float)a[0], (float)b[0], fmaf((float)a[1], (float)b[1], c));
#endif
}

static __device__ __forceinline__ half2_t h2bc(const unsigned* wsu, int idx) {
    h2u t; t.u = wsu[idx]; return t.v;
}

// One edge's MLP given packed-half endpoint rows and edge attrs.
static __device__ __forceinline__ float edge_one(half8_t rs, half8_t rt,
                                                 float fea, float feaT,
                                                 const float* __restrict__ wsf,
                                                 const unsigned* __restrict__ wsu) {
    half8_t sv8 = rs + rt;      // 4x v_pk_add_f16 (pad lanes harmless)
    half8_t dv8 = rs - rt;
    half2_t sv[3] = { __builtin_shufflevector(sv8, sv8, 0, 1),
                      __builtin_shufflevector(sv8, sv8, 2, 3),
                      __builtin_shufflevector(sv8, sv8, 4, 5) };
    half2_t dv[3] = { __builtin_shufflevector(dv8, dv8, 0, 1),
                      __builtin_shufflevector(dv8, dv8, 2, 3),
                      __builtin_shufflevector(dv8, dv8, 4, 5) };

    float cacc[10], macc[10];
#pragma unroll
    for (int j = 0; j < 10; ++j) { cacc[j] = wsf[j]; macc[j] = 0.0f; }
#pragma unroll
    for (int k = 0; k < 3; ++k) {
#pragma unroll
        for (int j = 0; j < 10; ++j) {
            cacc[j] = fdot2(sv[k], h2bc(wsu, 16 + k * 10 + j), cacc[j]);
            macc[j] = fdot2(dv[k], h2bc(wsu, 48 + k * 10 + j), macc[j]);
        }
    }

    _Float16 feah  = (_Float16)fea,  feaTh = (_Float16)feaT;
    half2_t fea2  = { feah,  feah  };
    half2_t feaT2 = { feaTh, feaTh };
    half2_t zero2 = { (_Float16)0.0f, (_Float16)0.0f };

    float z = wsf[10];
#pragma unroll
    for (int jp = 0; jp < 5; ++jp) {
        half2_t c2 = { (_Float16)cacc[2 * jp], (_Float16)cacc[2 * jp + 1] };
        half2_t m2 = { (_Float16)macc[2 * jp], (_Float16)macc[2 * jp + 1] };
        half2_t w12 = h2bc(wsu, 80 + jp);
        half2_t af2 = __builtin_elementwise_fma(fea2,  w12, c2 + m2);
        half2_t ar2 = __builtin_elementwise_fma(feaT2, w12, c2 - m2);
        half2_t h2  = __builtin_elementwise_max(af2, zero2) +
                      __builtin_elementwise_max(ar2, zero2);
        z = fdot2(h2, h2bc(wsu, 88 + jp), z);
    }
    return 1.0f / (1.0f + __expf(-z));
}

__launch_bounds__(256, 8)
__global__ void edge_mlp(const half8_t* __restrict__ xp, const int* __restrict__ ei,
                         const float* __restrict__ ea, const float* __restrict__ eaT,
                         const float* __restrict__ wsf, float* __restrict__ out, int E) {
    const unsigned* wsu = (const unsigned*)wsf;
    int g = blockIdx.x * 256 + threadIdx.x;
    int e0 = 2 * g;
    if (e0 + 1 < E) {
        int2_v   s2 = __builtin_nontemporal_load((const int2_v*)(ei + e0));
        int2_v   t2 = __builtin_nontemporal_load((const int2_v*)(ei + E + e0));
        float2_v fa = __builtin_nontemporal_load((const float2_v*)(ea + e0));
        float2_v fT = __builtin_nontemporal_load((const float2_v*)(eaT + e0));
        half8_t rs0 = xp[s2[0]], rt0 = xp[t2[0]];   // 16B gathers (L2-resident)
        half8_t rs1 = xp[s2[1]], rt1 = xp[t2[1]];
        float2_v r;
        r[0] = edge_one(rs0, rt0, fa[0], fT[0], wsf, wsu);
        r[1] = edge_one(rs1, rt1, fa[1], fT[1], wsf, wsu);
        __builtin_nontemporal_store(r, (float2_v*)(out + e0));
    } else if (e0 < E) {
        int si = ei[e0], ti = ei[E + e0];
        float r = edge_one(xp[si], xp[ti], ea[e0], eaT[e0], wsf, wsu);
        out[e0] = r;
    }
}

extern "C" void kernel_launch(void* const* d_in, const int* in_sizes, int n_in,
                              void* d_out, int out_size, void* d_ws, size_t ws_size,
                              hipStream_t stream) {
    const float* x   = (const float*)d_in[0];
    const int*   ei  = (const int*)d_in[1];
    const float* ea  = (const float*)d_in[2];
    const float* eaT = (const float*)d_in[3];
    const float* W1  = (const float*)d_in[4];
    const float* b1  = (const float*)d_in[5];
    const float* W2  = (const float*)d_in[6];
    const float* b2  = (const float*)d_in[7];
    float* out = (float*)d_out;
    float* ws  = (float*)d_ws;
    int E = in_sizes[2];          // N_EDGES
    int N = in_sizes[0] / 6;      // N_NODES

    int pblocks = (N + 255) / 256;
    prep<<<pblocks, 256, 0, stream>>>(W1, b1, W2, b2, x, ws, N);

    const half8_t* xp = (const half8_t*)((char*)d_ws + 4096);
    int nthreads = (E + 1) / 2;
    int blocks = (nthreads + 255) / 256;
    edge_mlp<<<blocks, 256, 0, stream>>>(xp, ei, ea, eaT, ws, out, E);
}

// Round 5
// 190.522 us; speedup vs baseline: 1.0381x; 1.0381x over previous
//
#include <hip/hip_runtime.h>
#include <hip/hip_fp16.h>

// EdgeMLP: out[e] = sigmoid( 0.5*dot(relu(af)+relu(ar), W2[:,1]-W2[:,0]) + (b2[1]-b2[0]) )
// Sym/antisym decomposition shares layer-1 work between fwd and rev MLPs:
//   P = 0.5*(W1[0:6]+W1[6:12]), M = 0.5*(W1[0:6]-W1[6:12])
//   cacc = b1 + P^T(xs+xt); macc = M^T(xs-xt)
//   af = cacc+macc+ea*w12, ar = cacc-macc+eaT*w12
//
// R4 post-mortem: VALU halved, time unchanged -> gather-bound. Fitted ~3.7
// cyc per L1 miss per CU = TCP miss/fill path saturated (x-table 1.6MB vs
// 32KB L1, ~0% hit). R5: bypass L1 on gathers with `global_load_dwordx4 ..
// sc0` (L2 residency preserved; NO nt on gathers), 4 edges/thread, x4
// stream loads/stores.
//
// d_ws layout:
//   float [0,10)  b1 (cacc init)     float [10] b2d
//   uint  [16,46)  P2[k][j]  (half2 of P[2k][j],P[2k+1][j]),  k<3, j<10
//   uint  [48,78)  M2[k][j]
//   uint  [80,85)  w12_2[jp] (half2 pairs of W1[12][:])
//   uint  [88,93)  w2d_2[jp] (half2 pairs of 0.5*(W2[j][1]-W2[j][0]))
//   byte 4096+:    packed x, 16B/node = 6 fp16 + 2 pad

typedef _Float16 half2_t  __attribute__((ext_vector_type(2)));
typedef _Float16 half8_t  __attribute__((ext_vector_type(8)));
typedef float    float4_v __attribute__((ext_vector_type(4)));
typedef int      int4_v   __attribute__((ext_vector_type(4)));

union h2u { __half2 h; unsigned u; half2_t v; };

__global__ void prep(const float* __restrict__ W1, const float* __restrict__ b1,
                     const float* __restrict__ W2, const float* __restrict__ b2,
                     const float* __restrict__ x, float* __restrict__ wsf, int N) {
    int t = blockIdx.x * 256 + threadIdx.x;
    if (t < N) {   // pack x row t -> 6 fp16 + 2 pad (16B, aligned)
        const float2* xr = (const float2*)x;
        float2 a0 = xr[3 * t], a1 = xr[3 * t + 1], a2 = xr[3 * t + 2];
        union { __half2 h[4]; float4 f; } pk;
        pk.h[0] = __floats2half2_rn(a0.x, a0.y);
        pk.h[1] = __floats2half2_rn(a1.x, a1.y);
        pk.h[2] = __floats2half2_rn(a2.x, a2.y);
        pk.h[3] = __floats2half2_rn(0.0f, 0.0f);
        ((float4*)((char*)wsf + 4096))[t] = pk.f;
    }
    if (blockIdx.x == 0) {
        unsigned* wsu = (unsigned*)wsf;
        int u = threadIdx.x;
        if (u < 10) wsf[u] = b1[u];
        if (u == 0) wsf[10] = b2[1] - b2[0];
        if (u < 30) {                       // P2 / M2: i-pairs (2k, 2k+1)
            int k = u / 10, j = u % 10;
            float a0 = W1[(2 * k) * 10 + j],     c0 = W1[(2 * k + 6) * 10 + j];
            float a1 = W1[(2 * k + 1) * 10 + j], c1 = W1[(2 * k + 7) * 10 + j];
            h2u p, m;
            p.h = __floats2half2_rn(0.5f * (a0 + c0), 0.5f * (a1 + c1));
            m.h = __floats2half2_rn(0.5f * (a0 - c0), 0.5f * (a1 - c1));
            wsu[16 + u] = p.u;
            wsu[48 + u] = m.u;
        }
        if (u < 5) {                        // j-pairs (2u, 2u+1)
            h2u a, b;
            a.h = __floats2half2_rn(W1[120 + 2 * u], W1[120 + 2 * u + 1]);
            b.h = __floats2half2_rn(0.5f * (W2[(2 * u) * 2 + 1] - W2[(2 * u) * 2]),
                                    0.5f * (W2[(2 * u + 1) * 2 + 1] - W2[(2 * u + 1) * 2]));
            wsu[80 + u] = a.u;
            wsu[88 + u] = b.u;
        }
    }
}

static __device__ __forceinline__ float fdot2(half2_t a, half2_t b, float c) {
#if __has_builtin(__builtin_amdgcn_fdot2)
    return __builtin_amdgcn_fdot2(a, b, c, false);
#else
    return fmaf((float)a[0], (float)b[0], fmaf((float)a[1], (float)b[1], c));
#endif
}

static __device__ __forceinline__ half2_t h2bc(const unsigned* wsu, int idx) {
    h2u t; t.u = wsu[idx]; return t.v;
}

// 16B gather that bypasses L1 (sc0) but caches in L2. Result is NOT
// vmcnt-tracked by the compiler -> must pass through gather_fence() before use.
static __device__ __forceinline__ half8_t gather16_sc0(const half8_t* base, int idx) {
    half8_t r;
    const half8_t* p = base + idx;
    asm volatile("global_load_dwordx4 %0, %1, off sc0" : "=v"(r) : "v"(p));
    return r;
}

// One edge's MLP given packed-half endpoint rows and edge attrs.
static __device__ __forceinline__ float edge_one(half8_t rs, half8_t rt,
                                                 float fea, float feaT,
                                                 const float* __restrict__ wsf,
                                                 const unsigned* __restrict__ wsu) {
    half8_t sv8 = rs + rt;      // v_pk_add_f16 (pad lanes harmless)
    half8_t dv8 = rs - rt;
    half2_t sv[3] = { __builtin_shufflevector(sv8, sv8, 0, 1),
                      __builtin_shufflevector(sv8, sv8, 2, 3),
                      __builtin_shufflevector(sv8, sv8, 4, 5) };
    half2_t dv[3] = { __builtin_shufflevector(dv8, dv8, 0, 1),
                      __builtin_shufflevector(dv8, dv8, 2, 3),
                      __builtin_shufflevector(dv8, dv8, 4, 5) };

    float cacc[10], macc[10];
#pragma unroll
    for (int j = 0; j < 10; ++j) { cacc[j] = wsf[j]; macc[j] = 0.0f; }
#pragma unroll
    for (int k = 0; k < 3; ++k) {
#pragma unroll
        for (int j = 0; j < 10; ++j) {
            cacc[j] = fdot2(sv[k], h2bc(wsu, 16 + k * 10 + j), cacc[j]);
            macc[j] = fdot2(dv[k], h2bc(wsu, 48 + k * 10 + j), macc[j]);
        }
    }

    _Float16 feah  = (_Float16)fea,  feaTh = (_Float16)feaT;
    half2_t fea2  = { feah,  feah  };
    half2_t feaT2 = { feaTh, feaTh };
    half2_t zero2 = { (_Float16)0.0f, (_Float16)0.0f };

    float z = wsf[10];
#pragma unroll
    for (int jp = 0; jp < 5; ++jp) {
        half2_t c2 = { (_Float16)cacc[2 * jp], (_Float16)cacc[2 * jp + 1] };
        half2_t m2 = { (_Float16)macc[2 * jp], (_Float16)macc[2 * jp + 1] };
        half2_t w12 = h2bc(wsu, 80 + jp);
        half2_t af2 = __builtin_elementwise_fma(fea2,  w12, c2 + m2);
        half2_t ar2 = __builtin_elementwise_fma(feaT2, w12, c2 - m2);
        half2_t h2  = __builtin_elementwise_max(af2, zero2) +
                      __builtin_elementwise_max(ar2, zero2);
        z = fdot2(h2, h2bc(wsu, 88 + jp), z);
    }
    return 1.0f / (1.0f + __expf(-z));
}

// 4 edges/thread: x4 stream loads, 8 L1-bypass gathers in flight, x4 store.
__launch_bounds__(256, 4)
__global__ void edge_mlp(const half8_t* __restrict__ xp, const int* __restrict__ ei,
                         const float* __restrict__ ea, const float* __restrict__ eaT,
                         const float* __restrict__ wsf, float* __restrict__ out, int E) {
    const unsigned* wsu = (const unsigned*)wsf;
    int g = blockIdx.x * 256 + threadIdx.x;
    int e0 = 4 * g;
    if (e0 + 3 < E) {
        int4_v   s4 = __builtin_nontemporal_load((const int4_v*)(ei + e0));
        int4_v   t4 = __builtin_nontemporal_load((const int4_v*)(ei + E + e0));
        float4_v a4 = __builtin_nontemporal_load((const float4_v*)(ea + e0));
        float4_v T4 = __builtin_nontemporal_load((const float4_v*)(eaT + e0));

        half8_t rs0 = gather16_sc0(xp, s4[0]);
        half8_t rt0 = gather16_sc0(xp, t4[0]);
        half8_t rs1 = gather16_sc0(xp, s4[1]);
        half8_t rt1 = gather16_sc0(xp, t4[1]);
        half8_t rs2 = gather16_sc0(xp, s4[2]);
        half8_t rt2 = gather16_sc0(xp, t4[2]);
        half8_t rs3 = gather16_sc0(xp, s4[3]);
        half8_t rt3 = gather16_sc0(xp, t4[3]);
        // Drain ALL outstanding vector loads (covers the untracked asm loads).
        asm volatile("s_waitcnt vmcnt(0)"
                     : "+v"(rs0), "+v"(rt0), "+v"(rs1), "+v"(rt1),
                       "+v"(rs2), "+v"(rt2), "+v"(rs3), "+v"(rt3)
                     :: "memory");

        float4_v r;
        r[0] = edge_one(rs0, rt0, a4[0], T4[0], wsf, wsu);
        r[1] = edge_one(rs1, rt1, a4[1], T4[1], wsf, wsu);
        r[2] = edge_one(rs2, rt2, a4[2], T4[2], wsf, wsu);
        r[3] = edge_one(rs3, rt3, a4[3], T4[3], wsf, wsu);
        __builtin_nontemporal_store(r, (float4_v*)(out + e0));
    } else {
        for (int e = e0; e < E; ++e) {
            int si = ei[e], ti = ei[E + e];
            half8_t rs = ((const half8_t*)xp)[si];
            half8_t rt = ((const half8_t*)xp)[ti];
            out[e] = edge_one(rs, rt, ea[e], eaT[e], wsf, wsu);
        }
    }
}

extern "C" void kernel_launch(void* const* d_in, const int* in_sizes, int n_in,
                              void* d_out, int out_size, void* d_ws, size_t ws_size,
                              hipStream_t stream) {
    const float* x   = (const float*)d_in[0];
    const int*   ei  = (const int*)d_in[1];
    const float* ea  = (const float*)d_in[2];
    const float* eaT = (const float*)d_in[3];
    const float* W1  = (const float*)d_in[4];
    const float* b1  = (const float*)d_in[5];
    const float* W2  = (const float*)d_in[6];
    const float* b2  = (const float*)d_in[7];
    float* out = (float*)d_out;
    float* ws  = (float*)d_ws;
    int E = in_sizes[2];          // N_EDGES
    int N = in_sizes[0] / 6;      // N_NODES

    int pblocks = (N + 255) / 256;
    prep<<<pblocks, 256, 0, stream>>>(W1, b1, W2, b2, x, ws, N);

    const half8_t* xp = (const half8_t*)((char*)d_ws + 4096);
    int nthreads = (E + 3) / 4;
    int blocks = (nthreads + 255) / 256;
    edge_mlp<<<blocks, 256, 0, stream>>>(xp, ei, ea, eaT, ws, out, E);
}